// Round 8
// baseline (770.381 us; speedup 1.0000x reference)
//
#include <hip/hip_runtime.h>

// Residual VQ, Q=4. Stage 1: exact fp32 GEMM (R7 structure, proven).
// Stages 2-4: Gram-matrix score update acc[k] -= G[b,k] (G fp64-accumulated),
// best+second tracked; if margin < TAU, block-cooperative exact fp32 rescore
// of that point (same error class as the passing R2/R5/R7 GEMM).
// Residual/loss exact elementwise; quantized = sum of chosen codes.
//
// d_out: quantized [8,64,128,128] (8388608 f32) | indices as float
//        [8,128,128,4] (524288) | commit_loss [4].
// d_ws: G [512][512] | cbS [64][512] striped | csq [512].

#define NPTS   131072
#define CH     64
#define KCODE  512
#define NQ     4
#define HW     16384
#define BPTS   64
#define BTHR   256
#define CCH    8
#define NCHK   8
#define TAU    1.0e-2f

__device__ __forceinline__ void load_lds16(const float* g, float* l) {
    __builtin_amdgcn_global_load_lds(
        (const __attribute__((address_space(1))) void*)g,
        (__attribute__((address_space(3))) void*)l, 16, 0, 0);
}

// cbS[c*512 + pos] = cb[k*64 + c], pos(k) = i*128 + cg*4 + j for k = cg*16+i*4+j
__global__ void prep_cbS(const float* __restrict__ cb, float* __restrict__ cbS) {
    int g = blockIdx.x * 256 + threadIdx.x;
    int c = g >> 9, pos = g & 511;
    int i = pos >> 7, cg = (pos >> 2) & 31, j = pos & 3;
    int k = cg * 16 + i * 4 + j;
    cbS[g] = cb[k * CH + c];
}

__global__ void prep_csq(const float* __restrict__ cb, float* __restrict__ csq) {
    int k = blockIdx.x * 256 + threadIdx.x;
    if (k < KCODE) {
        const float4* row = (const float4*)(cb + (size_t)k * CH);
        float a0 = 0.f, a1 = 0.f, a2 = 0.f, a3 = 0.f;
#pragma unroll
        for (int j = 0; j < CH / 4; ++j) {
            float4 v = row[j];
            a0 = fmaf(v.x, v.x, a0); a1 = fmaf(v.y, v.y, a1);
            a2 = fmaf(v.z, v.z, a2); a3 = fmaf(v.w, v.w, a3);
        }
        csq[k] = (a0 + a1) + (a2 + a3);
    }
}

// G[kb][k] = dot(cb[kb], cb[k]), fp64-accumulated then rounded (err ~ulp)
__global__ void prep_gram(const float* __restrict__ cb, float* __restrict__ G) {
    __shared__ float srow[CH];
    const int kb = blockIdx.x;
    if (threadIdx.x < CH / 4)
        ((float4*)srow)[threadIdx.x] =
            ((const float4*)(cb + (size_t)kb * CH))[threadIdx.x];
    __syncthreads();
#pragma unroll
    for (int r = 0; r < 2; ++r) {
        int k = threadIdx.x + r * 256;
        const float* row = cb + (size_t)k * CH;
        double a = 0.0;
        for (int j = 0; j < CH; ++j) a += (double)srow[j] * (double)row[j];
        G[(size_t)kb * KCODE + k] = (float)a;
    }
}

__global__ __launch_bounds__(BTHR)
__attribute__((amdgpu_waves_per_eu(3, 3)))
void rvq_main(
    const float* __restrict__ x, const float* __restrict__ cb,
    const float* __restrict__ cbS, const float* __restrict__ csq_g,
    const float* __restrict__ G,
    float* __restrict__ out_quant, float* __restrict__ out_idx,
    float* __restrict__ out_loss)
{
    __shared__ __align__(16) float s_res[CH * BPTS];        // 16 KB
    __shared__ __align__(16) float s_buf[2][CCH * KCODE];   // 32 KB
    __shared__ __align__(16) float s_csq[KCODE];            // 2 KB
    __shared__ int   s_bidx[BPTS];
    __shared__ int   s_idx4[BPTS * NQ];
    __shared__ float s_ls[4 * BPTS];
    __shared__ unsigned int s_mask[2];
    __shared__ float s_rwB[4];
    __shared__ int   s_rwI[4];

    const int tid  = threadIdx.x;
    const int lane = tid & 63;
    const int w    = tid >> 6;
    const int cg   = tid & 31;
    const int pg   = tid >> 5;

    const int n0  = blockIdx.x * BPTS;
    const int b   = n0 >> 14;
    const int hw0 = n0 & (HW - 1);
    const float* xbase = x + (size_t)b * CH * HW + hw0;

    // ---- prefetch stage-1 chunk 0; load x tile + csq ----
#pragma unroll
    for (int r = 0; r < 4; ++r) {
        int off = (w * 4 + r) * 256;
        load_lds16(cbS + off + lane * 4, &s_buf[0][off]);
    }
    for (int j = tid; j < CH * BPTS / 4; j += BTHR) {
        int c = j >> 4, p4 = j & 15;
        *(float4*)&s_res[c * BPTS + p4 * 4] =
            *(const float4*)(xbase + (size_t)c * HW + p4 * 4);
    }
    for (int j = tid; j < KCODE; j += BTHR) s_csq[j] = csq_g[j];
    __syncthreads();

    float lossq[NQ], idxf[NQ];

    // ---- acc init = -csq/2 ----
    float acc[8][16];
    {
        const float4* cq4 = (const float4*)(s_csq + cg * 16);
        float4 c0 = cq4[0], c1 = cq4[1], c2 = cq4[2], c3 = cq4[3];
        float ci[16] = {c0.x, c0.y, c0.z, c0.w, c1.x, c1.y, c1.z, c1.w,
                        c2.x, c2.y, c2.z, c2.w, c3.x, c3.y, c3.z, c3.w};
#pragma unroll
        for (int p = 0; p < 8; ++p)
#pragma unroll
            for (int n = 0; n < 16; ++n) acc[p][n] = -0.5f * ci[n];
    }

    // ---- stage-1 GEMM: 8 chunks x 8 channels, double-buffered (R7) ----
    for (int chk = 0; chk < NCHK; ++chk) {
        if (chk < NCHK - 1) {
            const float* src = cbS + (chk + 1) * (CCH * KCODE);
            float* dst = s_buf[(chk + 1) & 1];
#pragma unroll
            for (int r = 0; r < 4; ++r) {
                int off = (w * 4 + r) * 256;
                load_lds16(src + off + lane * 4, dst + off);
            }
        }
        const float* bufp = s_buf[chk & 1];
#pragma unroll 2
        for (int c = 0; c < CCH; ++c) {
            const float* ar = &s_res[(chk * CCH + c) * BPTS + pg * 8];
            float4 a0 = *(const float4*)(ar + 0);
            float4 a1 = *(const float4*)(ar + 4);
            float av[8] = {a0.x, a0.y, a0.z, a0.w, a1.x, a1.y, a1.z, a1.w};
            const float* br = &bufp[c * KCODE + cg * 4];
#pragma unroll
            for (int nb = 0; nb < 4; ++nb) {
                float4 bq = *(const float4*)(br + nb * 128);
#pragma unroll
                for (int p = 0; p < 8; ++p) {
                    acc[p][nb * 4 + 0] = fmaf(av[p], bq.x, acc[p][nb * 4 + 0]);
                    acc[p][nb * 4 + 1] = fmaf(av[p], bq.y, acc[p][nb * 4 + 1]);
                    acc[p][nb * 4 + 2] = fmaf(av[p], bq.z, acc[p][nb * 4 + 2]);
                    acc[p][nb * 4 + 3] = fmaf(av[p], bq.w, acc[p][nb * 4 + 3]);
                }
            }
        }
        __syncthreads();
    }

    // ---- stage-1 select: per-p argmax + half-wave butterfly ----
#pragma unroll
    for (int p = 0; p < 8; ++p) {
        float B = acc[p][0]; int I = cg * 16;
#pragma unroll
        for (int n = 1; n < 16; ++n)
            if (acc[p][n] > B) { B = acc[p][n]; I = cg * 16 + n; }
#pragma unroll
        for (int m = 1; m <= 16; m <<= 1) {
            float oB = __shfl_xor(B, m, 64);
            int   oI = __shfl_xor(I, m, 64);
            if (oB > B || (oB == B && oI < I)) { B = oB; I = oI; }
        }
        if (cg == 0) {
            s_bidx[pg * 8 + p] = I;
            s_idx4[(pg * 8 + p) * 4 + 0] = I;
        }
    }
    __syncthreads();
    if (tid < BPTS) idxf[0] = (float)s_bidx[tid];

    // ---- residual update + loss (stage 1) ----
    {
        const int p  = tid & 63;
        const int cq = tid >> 6;
        int bix = s_bidx[p];
        const float4* crow = (const float4*)(cb + (size_t)bix * CH + cq * 16);
        float l0 = 0.f, l1 = 0.f, l2 = 0.f, l3 = 0.f;
#pragma unroll
        for (int i = 0; i < 4; ++i) {
            float4 v = crow[i];
            int c = cq * 16 + i * 4;
            float r0 = s_res[(c + 0) * BPTS + p] - v.x;
            float r1 = s_res[(c + 1) * BPTS + p] - v.y;
            float r2 = s_res[(c + 2) * BPTS + p] - v.z;
            float r3 = s_res[(c + 3) * BPTS + p] - v.w;
            s_res[(c + 0) * BPTS + p] = r0;
            s_res[(c + 1) * BPTS + p] = r1;
            s_res[(c + 2) * BPTS + p] = r2;
            s_res[(c + 3) * BPTS + p] = r3;
            l0 = fmaf(r0, r0, l0); l1 = fmaf(r1, r1, l1);
            l2 = fmaf(r2, r2, l2); l3 = fmaf(r3, r3, l3);
        }
        s_ls[cq * BPTS + p] = (l0 + l1) + (l2 + l3);
    }
    __syncthreads();
    if (tid < BPTS)
        lossq[0] = (s_ls[0 * BPTS + tid] + s_ls[1 * BPTS + tid]) +
                   (s_ls[2 * BPTS + tid] + s_ls[3 * BPTS + tid]);

    // ---- stages 2..4: Gram update + margin-guarded fallback ----
    for (int q = 1; q < NQ; ++q) {
        int bix8[8];
#pragma unroll
        for (int p = 0; p < 8; ++p) bix8[p] = s_bidx[pg * 8 + p];
        if (tid < 2) s_mask[tid] = 0;
        __syncthreads();   // everyone read old bidx; mask reset visible

#pragma unroll
        for (int p = 0; p < 8; ++p) {
            const float4* grow =
                (const float4*)(G + (size_t)bix8[p] * KCODE + cg * 16);
#pragma unroll
            for (int nb = 0; nb < 4; ++nb) {
                float4 g = grow[nb];
                acc[p][nb * 4 + 0] -= g.x;
                acc[p][nb * 4 + 1] -= g.y;
                acc[p][nb * 4 + 2] -= g.z;
                acc[p][nb * 4 + 3] -= g.w;
            }
            float B = acc[p][0]; int I = cg * 16; float B2 = -3.4e38f;
#pragma unroll
            for (int n = 1; n < 16; ++n) {
                float v = acc[p][n];
                if (v > B)      { B2 = B; B = v; I = cg * 16 + n; }
                else if (v > B2) B2 = v;
            }
#pragma unroll
            for (int m = 1; m <= 16; m <<= 1) {
                float oB  = __shfl_xor(B, m, 64);
                int   oI  = __shfl_xor(I, m, 64);
                float oB2 = __shfl_xor(B2, m, 64);
                float nB2;
                if (oB > B)       { nB2 = fmaxf(B, oB2); B = oB; I = oI; }
                else if (oB == B) { nB2 = fmaxf(B2, oB2); if (oI < I) I = oI; }
                else              { nB2 = fmaxf(B2, oB); }
                B2 = nB2;
            }
            if (cg == 0) {
                s_bidx[pg * 8 + p] = I;
                s_idx4[(pg * 8 + p) * 4 + q] = I;
                if (B - B2 < TAU)
                    atomicOr(&s_mask[(pg * 8 + p) >> 5],
                             1u << ((pg * 8 + p) & 31));
            }
        }
        __syncthreads();

        // ---- exact rescore of margin-flagged points (rare, uniform loop) ----
        unsigned long long mask =
            (unsigned long long)s_mask[0] |
            ((unsigned long long)s_mask[1] << 32);
        while (mask) {
            int p = (int)__builtin_ctzll(mask);
            mask &= mask - 1;
            float Bb = -3.4e38f; int Ib = 0;
#pragma unroll
            for (int rr = 0; rr < 2; ++rr) {
                int k = tid + rr * 256;
                const float4* crow = (const float4*)(cb + (size_t)k * CH);
                float d0 = 0.f, d1 = 0.f, d2 = 0.f, d3 = 0.f;
#pragma unroll
                for (int j = 0; j < 16; ++j) {
                    float4 v = crow[j];
                    d0 = fmaf(v.x, s_res[(j * 4 + 0) * BPTS + p], d0);
                    d1 = fmaf(v.y, s_res[(j * 4 + 1) * BPTS + p], d1);
                    d2 = fmaf(v.z, s_res[(j * 4 + 2) * BPTS + p], d2);
                    d3 = fmaf(v.w, s_res[(j * 4 + 3) * BPTS + p], d3);
                }
                float s = fmaf(-0.5f, s_csq[k], (d0 + d1) + (d2 + d3));
                if (s > Bb) { Bb = s; Ib = k; }   // k ascending within thread
            }
#pragma unroll
            for (int m = 1; m <= 32; m <<= 1) {
                float oB = __shfl_xor(Bb, m, 64);
                int   oI = __shfl_xor(Ib, m, 64);
                if (oB > Bb || (oB == Bb && oI < Ib)) { Bb = oB; Ib = oI; }
            }
            if (lane == 0) { s_rwB[w] = Bb; s_rwI[w] = Ib; }
            __syncthreads();
            float fB = s_rwB[0]; int fI = s_rwI[0];
#pragma unroll
            for (int ww = 1; ww < 4; ++ww) {
                float tB = s_rwB[ww]; int tI = s_rwI[ww];
                if (tB > fB || (tB == fB && tI < fI)) { fB = tB; fI = tI; }
            }
            if (tid == 0) { s_bidx[p] = fI; s_idx4[p * 4 + q] = fI; }
            __syncthreads();
        }
        if (tid < BPTS) idxf[q] = (float)s_bidx[tid];

        // ---- residual update + loss ----
        {
            const int p  = tid & 63;
            const int cq = tid >> 6;
            int bix = s_bidx[p];
            const float4* crow = (const float4*)(cb + (size_t)bix * CH + cq * 16);
            float l0 = 0.f, l1 = 0.f, l2 = 0.f, l3 = 0.f;
#pragma unroll
            for (int i = 0; i < 4; ++i) {
                float4 v = crow[i];
                int c = cq * 16 + i * 4;
                float r0 = s_res[(c + 0) * BPTS + p] - v.x;
                float r1 = s_res[(c + 1) * BPTS + p] - v.y;
                float r2 = s_res[(c + 2) * BPTS + p] - v.z;
                float r3 = s_res[(c + 3) * BPTS + p] - v.w;
                s_res[(c + 0) * BPTS + p] = r0;
                s_res[(c + 1) * BPTS + p] = r1;
                s_res[(c + 2) * BPTS + p] = r2;
                s_res[(c + 3) * BPTS + p] = r3;
                l0 = fmaf(r0, r0, l0); l1 = fmaf(r1, r1, l1);
                l2 = fmaf(r2, r2, l2); l3 = fmaf(r3, r3, l3);
            }
            s_ls[cq * BPTS + p] = (l0 + l1) + (l2 + l3);
        }
        __syncthreads();
        if (tid < BPTS)
            lossq[q] = (s_ls[0 * BPTS + tid] + s_ls[1 * BPTS + tid]) +
                       (s_ls[2 * BPTS + tid] + s_ls[3 * BPTS + tid]);
    }

    // ---- epilogue: quantized = sum of 4 chosen code rows (sequential) ----
    {
        const int p  = tid & 63;
        const int cq = tid >> 6;
        int e0 = s_idx4[p * 4 + 0], e1 = s_idx4[p * 4 + 1];
        int e2 = s_idx4[p * 4 + 2], e3 = s_idx4[p * 4 + 3];
        const float4* r0 = (const float4*)(cb + (size_t)e0 * CH + cq * 16);
        const float4* r1 = (const float4*)(cb + (size_t)e1 * CH + cq * 16);
        const float4* r2 = (const float4*)(cb + (size_t)e2 * CH + cq * 16);
        const float4* r3 = (const float4*)(cb + (size_t)e3 * CH + cq * 16);
        float* ob = out_quant + (size_t)b * CH * HW + hw0;
#pragma unroll
        for (int i = 0; i < 4; ++i) {
            float4 v0 = r0[i], v1 = r1[i], v2 = r2[i], v3 = r3[i];
            float s0 = ((v0.x + v1.x) + v2.x) + v3.x;
            float s1 = ((v0.y + v1.y) + v2.y) + v3.y;
            float s2 = ((v0.z + v1.z) + v2.z) + v3.z;
            float s3 = ((v0.w + v1.w) + v2.w) + v3.w;
            int c = cq * 16 + i * 4;
            ob[(size_t)(c + 0) * HW + p] = s0;
            ob[(size_t)(c + 1) * HW + p] = s1;
            ob[(size_t)(c + 2) * HW + p] = s2;
            ob[(size_t)(c + 3) * HW + p] = s3;
        }
    }

    if (tid < BPTS) {
        ((float4*)out_idx)[n0 + tid] =
            make_float4(idxf[0], idxf[1], idxf[2], idxf[3]);
#pragma unroll
        for (int qq = 0; qq < NQ; ++qq) {
            float v = lossq[qq];
            for (int off = 32; off > 0; off >>= 1) v += __shfl_down(v, off, 64);
            if (tid == 0)
                atomicAdd(&out_loss[qq], v * (1.0f / 8388608.0f));
        }
    }
}

extern "C" void kernel_launch(void* const* d_in, const int* in_sizes, int n_in,
                              void* d_out, int out_size, void* d_ws, size_t ws_size,
                              hipStream_t stream) {
    const float* x  = (const float*)d_in[0];
    const float* cb = (const float*)d_in[1];
    float* out       = (float*)d_out;
    float* out_quant = out;
    float* out_idx   = out + 8388608;
    float* out_loss  = out + 8388608 + 524288;

    float* G   = (float*)d_ws;                 // 512*512
    float* cbS = G + KCODE * KCODE;            // 64*512
    float* csq = cbS + CH * KCODE;             // 512

    hipMemsetAsync(out_loss, 0, NQ * sizeof(float), stream);
    prep_cbS<<<(CH * KCODE) / 256, 256, 0, stream>>>(cb, cbS);
    prep_csq<<<2, 256, 0, stream>>>(cb, csq);
    prep_gram<<<KCODE, 256, 0, stream>>>(cb, G);
    rvq_main<<<NPTS / BPTS, BTHR, 0, stream>>>(x, cb, cbS, csq, G,
                                               out_quant, out_idx, out_loss);
}